// Round 7
// baseline (47430.103 us; speedup 1.0000x reference)
//
#include <hip/hip_runtime.h>
#include <cstdint>
#include <cstddef>

// ============================================================================
// PointerNet: encoder LSTM (B=512,S=256,D=2,H=256) + autoregressive pointer
// decode with jax.random.categorical (threefry2x32 partitionable, key 42).
// Output: int32 indices [512][256], trajectory-exact vs JAX reference.
//
// R7: latency-bound fix (R5/R6 evidence: neither bytes nor load-instruction
// count moved dur; the bound is exposed L3 latency + 5 barriers/step).
// Decoder step restructured around the true dependency graph:
//   h_t --> [FUSED: attention_t (L3 loads)  ||  Wh·h_t partials (FMA+L2)]
//        --> argmax/idx_t --> Wi·din (din read directly from L2-hot encS row,
//        no LDS staging phase) --> activation --> h_{t+1}
// Barriers/step: 3 (was 5). Wh partials live in registers across the argmax.
// First decoder LSTM (din=0) peeled as prologue. Compaction (R6), RNG and
// tie-break semantics unchanged (verified exact R1-R6).
// ============================================================================

typedef float v4f __attribute__((ext_vector_type(4)));

#define WS_ENCW4_OFF  (2u << 20)                    // [256 k][256 u][4 g] f32
#define WS_DECWI4_OFF (3u << 20)
#define WS_DECWH4_OFF (4u << 20)
#define WS_ENCS_OFF   (5u << 20)                    // [512 b][256 s][256 k] f32
#define WS_NEEDED     ((size_t)(5u << 20) + (size_t)512 * 256 * 256 * 4)

__device__ __forceinline__ unsigned rotl32(unsigned x, int r) {
  return (x << r) | (x >> (32 - r));
}
__device__ __forceinline__ float sigm(float x) { return 1.f / (1.f + expf(-x)); }

// Threefry-2x32, 20 rounds (jax._src.prng schedule) — verified exact R1-R6.
__device__ __forceinline__ void tf2(unsigned k0, unsigned k1,
                                    unsigned& x0, unsigned& x1) {
  const unsigned k2 = k0 ^ k1 ^ 0x1BD11BDAu;
  x0 += k0; x1 += k1;
  x0 += x1; x1 = rotl32(x1, 13); x1 ^= x0;
  x0 += x1; x1 = rotl32(x1, 15); x1 ^= x0;
  x0 += x1; x1 = rotl32(x1, 26); x1 ^= x0;
  x0 += x1; x1 = rotl32(x1,  6); x1 ^= x0;
  x0 += k1; x1 += k2 + 1u;
  x0 += x1; x1 = rotl32(x1, 17); x1 ^= x0;
  x0 += x1; x1 = rotl32(x1, 29); x1 ^= x0;
  x0 += x1; x1 = rotl32(x1, 16); x1 ^= x0;
  x0 += x1; x1 = rotl32(x1, 24); x1 ^= x0;
  x0 += k2; x1 += k0 + 2u;
  x0 += x1; x1 = rotl32(x1, 13); x1 ^= x0;
  x0 += x1; x1 = rotl32(x1, 15); x1 ^= x0;
  x0 += x1; x1 = rotl32(x1, 26); x1 ^= x0;
  x0 += x1; x1 = rotl32(x1,  6); x1 ^= x0;
  x0 += k0; x1 += k1 + 3u;
  x0 += x1; x1 = rotl32(x1, 17); x1 ^= x0;
  x0 += x1; x1 = rotl32(x1, 29); x1 ^= x0;
  x0 += x1; x1 = rotl32(x1, 16); x1 ^= x0;
  x0 += x1; x1 = rotl32(x1, 24); x1 ^= x0;
  x0 += k1; x1 += k2 + 4u;
  x0 += x1; x1 = rotl32(x1, 13); x1 ^= x0;
  x0 += x1; x1 = rotl32(x1, 15); x1 ^= x0;
  x0 += x1; x1 = rotl32(x1, 26); x1 ^= x0;
  x0 += x1; x1 = rotl32(x1,  6); x1 ^= x0;
  x0 += k2; x1 += k0 + 5u;
}

// Repack W [1024 rows][256 k] row-major -> [k][u][gate] (float4 per (k,u)).
__global__ void repack_k(const float* __restrict__ eWh,
                         const float* __restrict__ dWi,
                         const float* __restrict__ dWh,
                         float* __restrict__ ws) {
  float* encW4 = (float*)((char*)ws + WS_ENCW4_OFF);
  float* decWi4 = (float*)((char*)ws + WS_DECWI4_OFF);
  float* decWh4 = (float*)((char*)ws + WS_DECWH4_OFF);
  const int n = blockIdx.x * blockDim.x + threadIdx.x;   // 65536 = 256k x 256u
  if (n >= 65536) return;
  const int k = n >> 8, u = n & 255;
#pragma unroll
  for (int g = 0; g < 4; ++g) {
    const int src = ((g << 8) + u) * 256 + k;
    const int dst = (n << 2) + g;
    encW4[dst] = eWh[src];
    decWi4[dst] = dWi[src];
    decWh4[dst] = dWh[src];
  }
}

__global__ void __launch_bounds__(1024)
ptrnet_kernel(const float* __restrict__ inp,    // [512][256][2]
              const float* __restrict__ eWi,    // [1024][2]
              const float* __restrict__ eBi, const float* __restrict__ eBh,
              const float* __restrict__ dBi, const float* __restrict__ dBh,
              int* __restrict__ out,            // [512][256]
              float* __restrict__ ws) {
  const int tid  = threadIdx.x;
  const int wave = tid >> 6, l = tid & 63;
  const int kq   = wave >> 2;               // K-quarter 0..3 (16 k4 each)
  const int uw   = wave & 3;                // u-slice 0..3
  const int uP   = (uw << 6) | l;           // this lane's unit in P1 (matmul)
  const int k4b  = kq << 4;
  const int bA   = tid >> 8;                // this thread's batch in P2/attn
  const int uA   = tid & 255;               // this thread's unit/slot in P2/attn
  const int b0   = blockIdx.x << 2;
  const int bG   = b0 + bA;

  const v4f* encW4  = (const v4f*)((char*)ws + WS_ENCW4_OFF);
  const v4f* decWi4 = (const v4f*)((char*)ws + WS_DECWI4_OFF);
  const v4f* decWh4 = (const v4f*)((char*)ws + WS_DECWH4_OFF);
  v4f* encS = (v4f*)((char*)ws + WS_ENCS_OFF);   // [b][s][64 k4] v4f

  __shared__ __align__(16) float hsF[2][1024];   // h dbuf: [buf][b*256+u]
  __shared__ __align__(16) v4f red[16][256];     // partials [kq*4+b][u] (gates)
  __shared__ short actS[4][256];                 // compacted active s list
  __shared__ short posS[4][256];                 // position of s in actS
  __shared__ float partV[4][4];
  __shared__ int   partI[4][4];

  // ---- activation-thread constants (keyed by uA) ----
  const float ebi_ = eBi[uA] + eBh[uA];
  const float ebf_ = eBi[256 + uA] + eBh[256 + uA];
  const float ebg_ = eBi[512 + uA] + eBh[512 + uA];
  const float ebo_ = eBi[768 + uA] + eBh[768 + uA];
  const float wxi0 = eWi[2 * uA], wxi1 = eWi[2 * uA + 1];
  const float wxf0 = eWi[2 * (256 + uA)], wxf1 = eWi[2 * (256 + uA) + 1];
  const float wxg0 = eWi[2 * (512 + uA)], wxg1 = eWi[2 * (512 + uA) + 1];
  const float wxo0 = eWi[2 * (768 + uA)], wxo1 = eWi[2 * (768 + uA) + 1];

  hsF[0][tid] = 0.f;
  __syncthreads();

  float c = 0.f;        // cell state for (bG, uA) — register-resident throughout
  int p = 0;

  // ---------------- encoder: 256 steps ----------------
  for (int t = 0; t < 256; ++t) {
    v4f a0 = (v4f)0.f, a1 = (v4f)0.f, a2 = (v4f)0.f, a3 = (v4f)0.f;
    const v4f* Wp = encW4 + uP;
    const v4f* hq = (const v4f*)&hsF[p][0];       // [4 b][64 k4]
#pragma unroll 2
    for (int kk = 0; kk < 16; ++kk) {
      const int k4 = k4b + kk;
      const v4f w0 = Wp[(k4 * 4 + 0) << 8];
      const v4f w1 = Wp[(k4 * 4 + 1) << 8];
      const v4f w2 = Wp[(k4 * 4 + 2) << 8];
      const v4f w3 = Wp[(k4 * 4 + 3) << 8];
      const v4f h0 = hq[k4];
      const v4f h1 = hq[64 + k4];
      const v4f h2 = hq[128 + k4];
      const v4f h3 = hq[192 + k4];
      a0 += w0 * h0.x + w1 * h0.y + w2 * h0.z + w3 * h0.w;
      a1 += w0 * h1.x + w1 * h1.y + w2 * h1.z + w3 * h1.w;
      a2 += w0 * h2.x + w1 * h2.y + w2 * h2.z + w3 * h2.w;
      a3 += w0 * h3.x + w1 * h3.y + w2 * h3.z + w3 * h3.w;
    }
    red[(kq << 2) | 0][uP] = a0;
    red[(kq << 2) | 1][uP] = a1;
    red[(kq << 2) | 2][uP] = a2;
    red[(kq << 2) | 3][uP] = a3;
    __syncthreads();                              // S_B: partials ready
    const v4f gv = red[bA][uA] + red[4 + bA][uA] + red[8 + bA][uA] + red[12 + bA][uA];
    const float2 xv = *(const float2*)(inp + (((bG) << 8) + t) * 2);
    const float ai = gv.x + ebi_ + wxi0 * xv.x + wxi1 * xv.y;
    const float af = gv.y + ebf_ + wxf0 * xv.x + wxf1 * xv.y;
    const float ag = gv.z + ebg_ + wxg0 * xv.x + wxg1 * xv.y;
    const float ao = gv.w + ebo_ + wxo0 * xv.x + wxo1 * xv.y;
    const float iv = sigm(ai), fv = sigm(af), gva = tanhf(ag), ov = sigm(ao);
    c = fv * c + iv * gva;
    const float hn = ov * tanhf(c);
    hsF[p ^ 1][(bA << 8) | uA] = hn;
    ((float*)encS)[(((bG << 8) | t) << 8) | uA] = hn;   // s-major row store
    __syncthreads();                              // S_C: new h ready
    p ^= 1;
  }

  // ---------------- decoder ----------------
  const float dbi_ = dBi[uA] + dBh[uA];
  const float dbf_ = dBi[256 + uA] + dBh[256 + uA];
  const float dbg_ = dBi[512 + uA] + dBh[512 + uA];
  const float dbo_ = dBi[768 + uA] + dBh[768 + uA];
  const float NEG_INF = __int_as_float((int)0xff800000);

  actS[bA][uA] = (short)uA;
  posS[bA][uA] = (short)uA;
  // no barrier needed here: actS first read is two barriers away

  // --- prologue: decoder LSTM step 0 (din = 0) ---
  {
    v4f a0 = (v4f)0.f, a1 = (v4f)0.f, a2 = (v4f)0.f, a3 = (v4f)0.f;
    const v4f* Wh = decWh4 + uP;
    const v4f* hq = (const v4f*)&hsF[p][0];
#pragma unroll 2
    for (int kk = 0; kk < 16; ++kk) {
      const int k4 = k4b + kk;
      const v4f w0 = Wh[(k4 * 4 + 0) << 8];
      const v4f w1 = Wh[(k4 * 4 + 1) << 8];
      const v4f w2 = Wh[(k4 * 4 + 2) << 8];
      const v4f w3 = Wh[(k4 * 4 + 3) << 8];
      const v4f h0 = hq[k4];
      const v4f h1 = hq[64 + k4];
      const v4f h2 = hq[128 + k4];
      const v4f h3 = hq[192 + k4];
      a0 += w0 * h0.x + w1 * h0.y + w2 * h0.z + w3 * h0.w;
      a1 += w0 * h1.x + w1 * h1.y + w2 * h1.z + w3 * h1.w;
      a2 += w0 * h2.x + w1 * h2.y + w2 * h2.z + w3 * h2.w;
      a3 += w0 * h3.x + w1 * h3.y + w2 * h3.z + w3 * h3.w;
    }
    red[(kq << 2) | 0][uP] = a0;
    red[(kq << 2) | 1][uP] = a1;
    red[(kq << 2) | 2][uP] = a2;
    red[(kq << 2) | 3][uP] = a3;
    __syncthreads();
    const v4f gv = red[bA][uA] + red[4 + bA][uA] + red[8 + bA][uA] + red[12 + bA][uA];
    const float iv = sigm(gv.x + dbi_), fv = sigm(gv.y + dbf_);
    const float gva = tanhf(gv.z + dbg_), ov = sigm(gv.w + dbo_);
    c = fv * c + iv * gva;
    hsF[p ^ 1][(bA << 8) | uA] = ov * tanhf(c);
    __syncthreads();
    p ^= 1;
  }

  // --- main loop: attention_t + Wh·h_t fused; then Wi·din; then activation ---
  for (int t = 0; t < 256; ++t) {
    const int cnt = 256 - t;
    const bool act = (uA < cnt);
    const int sIdx = act ? (int)actS[bA][uA] : 0;

    // FUSED PHASE: attention row dot (L3 latency) hidden under Wh·h FMA (L2)
    const v4f* Arow = encS + ((((size_t)bG << 8) | (unsigned)sIdx) << 6);
    const v4f* hrow = ((const v4f*)&hsF[p][0]) + (bA << 6);
    const v4f* hq   = (const v4f*)&hsF[p][0];
    const v4f* Wh   = decWh4 + uP;
    v4f a0 = (v4f)0.f, a1 = (v4f)0.f, a2 = (v4f)0.f, a3 = (v4f)0.f;
    float s0 = 0.f, s1 = 0.f, s2 = 0.f, s3 = 0.f;
#pragma unroll 8
    for (int kk = 0; kk < 16; ++kk) {
      const int k4 = k4b + kk;
      v4f e0 = (v4f)0.f, e1 = (v4f)0.f, e2 = (v4f)0.f, e3 = (v4f)0.f;
      if (act) {
        e0 = Arow[4 * kk + 0]; e1 = Arow[4 * kk + 1];
        e2 = Arow[4 * kk + 2]; e3 = Arow[4 * kk + 3];
      }
      const v4f w0 = Wh[(k4 * 4 + 0) << 8];
      const v4f w1 = Wh[(k4 * 4 + 1) << 8];
      const v4f w2 = Wh[(k4 * 4 + 2) << 8];
      const v4f w3 = Wh[(k4 * 4 + 3) << 8];
      const v4f h0 = hq[k4];
      const v4f h1 = hq[64 + k4];
      const v4f h2 = hq[128 + k4];
      const v4f h3 = hq[192 + k4];
      a0 += w0 * h0.x + w1 * h0.y + w2 * h0.z + w3 * h0.w;
      a1 += w0 * h1.x + w1 * h1.y + w2 * h1.z + w3 * h1.w;
      a2 += w0 * h2.x + w1 * h2.y + w2 * h2.z + w3 * h2.w;
      a3 += w0 * h3.x + w1 * h3.y + w2 * h3.z + w3 * h3.w;
      if (act) {
        const v4f f0 = hrow[4 * kk + 0], f1 = hrow[4 * kk + 1];
        const v4f f2 = hrow[4 * kk + 2], f3 = hrow[4 * kk + 3];
        s0 += e0.x * f0.x + e0.y * f0.y + e0.z * f0.z + e0.w * f0.w;
        s1 += e1.x * f1.x + e1.y * f1.y + e1.z * f1.z + e1.w * f1.w;
        s2 += e2.x * f2.x + e2.y * f2.y + e2.z * f2.z + e2.w * f2.w;
        s3 += e3.x * f3.x + e3.y * f3.y + e3.z * f3.z + e3.w * f3.w;
      }
    }
    float bv = NEG_INF;
    int bi = 0x7fffffff;
    if (act) {
      const float sc = (s0 + s1) + (s2 + s3);
      unsigned kk0 = 0u, kk1 = (unsigned)t;       // threefry (exact, R1-R6)
      tf2(0u, 42u, kk0, kk1);
      unsigned y0 = 0u, y1 = (unsigned)((bG << 8) + sIdx);
      tf2(kk0, kk1, y0, y1);
      const unsigned bits = y0 ^ y1;
      const float fr = __uint_as_float((bits >> 9) | 0x3f800000u) - 1.0f;
      const float uu = (fr > 0.f) ? fr : 1.17549435e-38f;
      const float gum = -logf(-logf(uu));
      bv = sc + gum;
      bi = sIdx;
    }
#pragma unroll
    for (int off = 32; off; off >>= 1) {
      const float ov2 = __shfl_xor(bv, off, 64);
      const int oi2 = __shfl_xor(bi, off, 64);
      if (ov2 > bv || (ov2 == bv && oi2 < bi)) { bv = ov2; bi = oi2; }
    }
    if (l == 0) { partV[bA][uw] = bv; partI[bA][uw] = bi; }
    __syncthreads();                              // S_D: argmax partials ready

    // all threads: combine argmax for ALL 4 batches (needed for Wi phase)
    int fiv[4];
#pragma unroll
    for (int bb = 0; bb < 4; ++bb) {
      float v = partV[bb][0]; int fi = partI[bb][0];
#pragma unroll
      for (int j = 1; j < 4; ++j) {
        const float vj = partV[bb][j];
        const int ij = partI[bb][j];
        if (vj > v || (vj == v && ij < fi)) { v = vj; fi = ij; }
      }
      fiv[bb] = fi;
    }
    if (uA == 0) {                                // one thread per batch
      const int fi = fiv[bA];
      out[(bG << 8) + t] = fi;
      const int pf = posS[bA][fi];                // swap-remove from active list
      const short ls = actS[bA][cnt - 1];
      actS[bA][pf] = ls;
      posS[bA][ls] = (short)pf;
    }

    // Wi·din partials; din rows are L2-hot (attention just read them)
    {
      const v4f* Wi = decWi4 + uP;
      const v4f* r0 = encS + ((((size_t)(b0 + 0) << 8) | (unsigned)fiv[0]) << 6);
      const v4f* r1 = encS + ((((size_t)(b0 + 1) << 8) | (unsigned)fiv[1]) << 6);
      const v4f* r2 = encS + ((((size_t)(b0 + 2) << 8) | (unsigned)fiv[2]) << 6);
      const v4f* r3 = encS + ((((size_t)(b0 + 3) << 8) | (unsigned)fiv[3]) << 6);
#pragma unroll 2
      for (int kk = 0; kk < 16; ++kk) {
        const int k4 = k4b + kk;
        const v4f w0 = Wi[(k4 * 4 + 0) << 8];
        const v4f w1 = Wi[(k4 * 4 + 1) << 8];
        const v4f w2 = Wi[(k4 * 4 + 2) << 8];
        const v4f w3 = Wi[(k4 * 4 + 3) << 8];
        const v4f d0 = r0[k4];
        const v4f d1 = r1[k4];
        const v4f d2 = r2[k4];
        const v4f d3 = r3[k4];
        a0 += w0 * d0.x + w1 * d0.y + w2 * d0.z + w3 * d0.w;
        a1 += w0 * d1.x + w1 * d1.y + w2 * d1.z + w3 * d1.w;
        a2 += w0 * d2.x + w1 * d2.y + w2 * d2.z + w3 * d2.w;
        a3 += w0 * d3.x + w1 * d3.y + w2 * d3.z + w3 * d3.w;
      }
    }
    red[(kq << 2) | 0][uP] = a0;
    red[(kq << 2) | 1][uP] = a1;
    red[(kq << 2) | 2][uP] = a2;
    red[(kq << 2) | 3][uP] = a3;
    __syncthreads();                              // S_B: partials ready

    // activation for (bA, uA) -> h_{t+1}
    const v4f gv = red[bA][uA] + red[4 + bA][uA] + red[8 + bA][uA] + red[12 + bA][uA];
    const float iv = sigm(gv.x + dbi_), fv = sigm(gv.y + dbf_);
    const float gva = tanhf(gv.z + dbg_), ov = sigm(gv.w + dbo_);
    c = fv * c + iv * gva;
    hsF[p ^ 1][(bA << 8) | uA] = ov * tanhf(c);
    __syncthreads();                              // S_C: new h ready
    p ^= 1;
  }
}

extern "C" void kernel_launch(void* const* d_in, const int* in_sizes, int n_in,
                              void* d_out, int out_size, void* d_ws, size_t ws_size,
                              hipStream_t stream) {
  (void)in_sizes; (void)n_in; (void)out_size;
  if (ws_size < WS_NEEDED) return;   // need ~139 MB scratch

  const float* inp = (const float*)d_in[0];
  const float* eWi = (const float*)d_in[1];
  const float* eWh = (const float*)d_in[2];
  const float* eBi = (const float*)d_in[3];
  const float* eBh = (const float*)d_in[4];
  const float* dWi = (const float*)d_in[5];
  const float* dWh = (const float*)d_in[6];
  const float* dBi = (const float*)d_in[7];
  const float* dBh = (const float*)d_in[8];
  int* out = (int*)d_out;
  float* wsf = (float*)d_ws;

  hipLaunchKernelGGL(repack_k, dim3(256), dim3(256), 0, stream, eWh, dWi, dWh, wsf);
  hipLaunchKernelGGL(ptrnet_kernel, dim3(128), dim3(1024), 0, stream,
                     inp, eWi, eBi, eBh, dBi, dBh, out, wsf);
}

// Round 8
// 30566.608 us; speedup vs baseline: 1.5517x; 1.5517x over previous
//
#include <hip/hip_runtime.h>
#include <cstdint>
#include <cstddef>

// ============================================================================
// PointerNet: encoder LSTM (B=512,S=256,D=2,H=256) + autoregressive pointer
// decode with jax.random.categorical (threefry2x32 partitionable, key 42).
// Output: int32 indices [512][256], trajectory-exact vs JAX reference.
//
// R8 = R7 structure (fused attention_t + Wh·h_t phase; argmax; Wi·din read
// directly from L2-hot encS row; activation; 3 barriers/step) with the R7
// spill bug fixed:
//  - R7 failure mode: __launch_bounds__(1024) defaulted to a 64-VGPR cap ->
//    ~100 live regs in the fused loop spilled to scratch (50 GB FETCH +
//    50 GB WRITE of pure spill traffic = the 47 ms).
//  - Fix 1: __launch_bounds__(1024, 4): 4 waves/EU = 1 block/CU (LDS forces
//    that anyway) -> 128-VGPR budget.
//  - Fix 2: Wh partials stored to LDS red[] BEFORE the argmax phase; Wi
//    phase accumulates fresh and read-modify-writes the slot. No v4f
//    accumulators live across barriers.
// ============================================================================

typedef float v4f __attribute__((ext_vector_type(4)));

#define WS_ENCW4_OFF  (2u << 20)                    // [256 k][256 u][4 g] f32
#define WS_DECWI4_OFF (3u << 20)
#define WS_DECWH4_OFF (4u << 20)
#define WS_ENCS_OFF   (5u << 20)                    // [512 b][256 s][256 k] f32
#define WS_NEEDED     ((size_t)(5u << 20) + (size_t)512 * 256 * 256 * 4)

__device__ __forceinline__ unsigned rotl32(unsigned x, int r) {
  return (x << r) | (x >> (32 - r));
}
__device__ __forceinline__ float sigm(float x) { return 1.f / (1.f + expf(-x)); }

// Threefry-2x32, 20 rounds (jax._src.prng schedule) — verified exact R1-R7.
__device__ __forceinline__ void tf2(unsigned k0, unsigned k1,
                                    unsigned& x0, unsigned& x1) {
  const unsigned k2 = k0 ^ k1 ^ 0x1BD11BDAu;
  x0 += k0; x1 += k1;
  x0 += x1; x1 = rotl32(x1, 13); x1 ^= x0;
  x0 += x1; x1 = rotl32(x1, 15); x1 ^= x0;
  x0 += x1; x1 = rotl32(x1, 26); x1 ^= x0;
  x0 += x1; x1 = rotl32(x1,  6); x1 ^= x0;
  x0 += k1; x1 += k2 + 1u;
  x0 += x1; x1 = rotl32(x1, 17); x1 ^= x0;
  x0 += x1; x1 = rotl32(x1, 29); x1 ^= x0;
  x0 += x1; x1 = rotl32(x1, 16); x1 ^= x0;
  x0 += x1; x1 = rotl32(x1, 24); x1 ^= x0;
  x0 += k2; x1 += k0 + 2u;
  x0 += x1; x1 = rotl32(x1, 13); x1 ^= x0;
  x0 += x1; x1 = rotl32(x1, 15); x1 ^= x0;
  x0 += x1; x1 = rotl32(x1, 26); x1 ^= x0;
  x0 += x1; x1 = rotl32(x1,  6); x1 ^= x0;
  x0 += k0; x1 += k1 + 3u;
  x0 += x1; x1 = rotl32(x1, 17); x1 ^= x0;
  x0 += x1; x1 = rotl32(x1, 29); x1 ^= x0;
  x0 += x1; x1 = rotl32(x1, 16); x1 ^= x0;
  x0 += x1; x1 = rotl32(x1, 24); x1 ^= x0;
  x0 += k1; x1 += k2 + 4u;
  x0 += x1; x1 = rotl32(x1, 13); x1 ^= x0;
  x0 += x1; x1 = rotl32(x1, 15); x1 ^= x0;
  x0 += x1; x1 = rotl32(x1, 26); x1 ^= x0;
  x0 += x1; x1 = rotl32(x1,  6); x1 ^= x0;
  x0 += k2; x1 += k0 + 5u;
}

// Repack W [1024 rows][256 k] row-major -> [k][u][gate] (float4 per (k,u)).
__global__ void repack_k(const float* __restrict__ eWh,
                         const float* __restrict__ dWi,
                         const float* __restrict__ dWh,
                         float* __restrict__ ws) {
  float* encW4 = (float*)((char*)ws + WS_ENCW4_OFF);
  float* decWi4 = (float*)((char*)ws + WS_DECWI4_OFF);
  float* decWh4 = (float*)((char*)ws + WS_DECWH4_OFF);
  const int n = blockIdx.x * blockDim.x + threadIdx.x;   // 65536 = 256k x 256u
  if (n >= 65536) return;
  const int k = n >> 8, u = n & 255;
#pragma unroll
  for (int g = 0; g < 4; ++g) {
    const int src = ((g << 8) + u) * 256 + k;
    const int dst = (n << 2) + g;
    encW4[dst] = eWh[src];
    decWi4[dst] = dWi[src];
    decWh4[dst] = dWh[src];
  }
}

__global__ void __launch_bounds__(1024, 4)
ptrnet_kernel(const float* __restrict__ inp,    // [512][256][2]
              const float* __restrict__ eWi,    // [1024][2]
              const float* __restrict__ eBi, const float* __restrict__ eBh,
              const float* __restrict__ dBi, const float* __restrict__ dBh,
              int* __restrict__ out,            // [512][256]
              float* __restrict__ ws) {
  const int tid  = threadIdx.x;
  const int wave = tid >> 6, l = tid & 63;
  const int kq   = wave >> 2;               // K-quarter 0..3 (16 k4 each)
  const int uw   = wave & 3;                // u-slice 0..3
  const int uP   = (uw << 6) | l;           // this lane's unit in P1 (matmul)
  const int k4b  = kq << 4;
  const int bA   = tid >> 8;                // this thread's batch in P2/attn
  const int uA   = tid & 255;               // this thread's unit/slot in P2/attn
  const int b0   = blockIdx.x << 2;
  const int bG   = b0 + bA;

  const v4f* encW4  = (const v4f*)((char*)ws + WS_ENCW4_OFF);
  const v4f* decWi4 = (const v4f*)((char*)ws + WS_DECWI4_OFF);
  const v4f* decWh4 = (const v4f*)((char*)ws + WS_DECWH4_OFF);
  v4f* encS = (v4f*)((char*)ws + WS_ENCS_OFF);   // [b][s][64 k4] v4f

  __shared__ __align__(16) float hsF[2][1024];   // h dbuf: [buf][b*256+u]
  __shared__ __align__(16) v4f red[16][256];     // partials [kq*4+b][u] (gates)
  __shared__ short actS[4][256];                 // compacted active s list
  __shared__ short posS[4][256];                 // position of s in actS
  __shared__ float partV[4][4];
  __shared__ int   partI[4][4];

  // ---- activation-thread constants (keyed by uA) ----
  const float ebi_ = eBi[uA] + eBh[uA];
  const float ebf_ = eBi[256 + uA] + eBh[256 + uA];
  const float ebg_ = eBi[512 + uA] + eBh[512 + uA];
  const float ebo_ = eBi[768 + uA] + eBh[768 + uA];
  const float wxi0 = eWi[2 * uA], wxi1 = eWi[2 * uA + 1];
  const float wxf0 = eWi[2 * (256 + uA)], wxf1 = eWi[2 * (256 + uA) + 1];
  const float wxg0 = eWi[2 * (512 + uA)], wxg1 = eWi[2 * (512 + uA) + 1];
  const float wxo0 = eWi[2 * (768 + uA)], wxo1 = eWi[2 * (768 + uA) + 1];

  hsF[0][tid] = 0.f;
  __syncthreads();

  float c = 0.f;        // cell state for (bG, uA) — register-resident throughout
  int p = 0;

  // ---------------- encoder: 256 steps ----------------
  for (int t = 0; t < 256; ++t) {
    v4f a0 = (v4f)0.f, a1 = (v4f)0.f, a2 = (v4f)0.f, a3 = (v4f)0.f;
    const v4f* Wp = encW4 + uP;
    const v4f* hq = (const v4f*)&hsF[p][0];       // [4 b][64 k4]
#pragma unroll 2
    for (int kk = 0; kk < 16; ++kk) {
      const int k4 = k4b + kk;
      const v4f w0 = Wp[(k4 * 4 + 0) << 8];
      const v4f w1 = Wp[(k4 * 4 + 1) << 8];
      const v4f w2 = Wp[(k4 * 4 + 2) << 8];
      const v4f w3 = Wp[(k4 * 4 + 3) << 8];
      const v4f h0 = hq[k4];
      const v4f h1 = hq[64 + k4];
      const v4f h2 = hq[128 + k4];
      const v4f h3 = hq[192 + k4];
      a0 += w0 * h0.x + w1 * h0.y + w2 * h0.z + w3 * h0.w;
      a1 += w0 * h1.x + w1 * h1.y + w2 * h1.z + w3 * h1.w;
      a2 += w0 * h2.x + w1 * h2.y + w2 * h2.z + w3 * h2.w;
      a3 += w0 * h3.x + w1 * h3.y + w2 * h3.z + w3 * h3.w;
    }
    red[(kq << 2) | 0][uP] = a0;
    red[(kq << 2) | 1][uP] = a1;
    red[(kq << 2) | 2][uP] = a2;
    red[(kq << 2) | 3][uP] = a3;
    __syncthreads();                              // S_B: partials ready
    const v4f gv = red[bA][uA] + red[4 + bA][uA] + red[8 + bA][uA] + red[12 + bA][uA];
    const float2 xv = *(const float2*)(inp + (((bG) << 8) + t) * 2);
    const float ai = gv.x + ebi_ + wxi0 * xv.x + wxi1 * xv.y;
    const float af = gv.y + ebf_ + wxf0 * xv.x + wxf1 * xv.y;
    const float ag = gv.z + ebg_ + wxg0 * xv.x + wxg1 * xv.y;
    const float ao = gv.w + ebo_ + wxo0 * xv.x + wxo1 * xv.y;
    const float iv = sigm(ai), fv = sigm(af), gva = tanhf(ag), ov = sigm(ao);
    c = fv * c + iv * gva;
    const float hn = ov * tanhf(c);
    hsF[p ^ 1][(bA << 8) | uA] = hn;
    ((float*)encS)[(((bG << 8) | t) << 8) | uA] = hn;   // s-major row store
    __syncthreads();                              // S_C: new h ready
    p ^= 1;
  }

  // ---------------- decoder ----------------
  const float dbi_ = dBi[uA] + dBh[uA];
  const float dbf_ = dBi[256 + uA] + dBh[256 + uA];
  const float dbg_ = dBi[512 + uA] + dBh[512 + uA];
  const float dbo_ = dBi[768 + uA] + dBh[768 + uA];
  const float NEG_INF = __int_as_float((int)0xff800000);

  actS[bA][uA] = (short)uA;
  posS[bA][uA] = (short)uA;

  // --- prologue: decoder LSTM step 0 (din = 0) ---
  {
    v4f a0 = (v4f)0.f, a1 = (v4f)0.f, a2 = (v4f)0.f, a3 = (v4f)0.f;
    const v4f* Wh = decWh4 + uP;
    const v4f* hq = (const v4f*)&hsF[p][0];
#pragma unroll 2
    for (int kk = 0; kk < 16; ++kk) {
      const int k4 = k4b + kk;
      const v4f w0 = Wh[(k4 * 4 + 0) << 8];
      const v4f w1 = Wh[(k4 * 4 + 1) << 8];
      const v4f w2 = Wh[(k4 * 4 + 2) << 8];
      const v4f w3 = Wh[(k4 * 4 + 3) << 8];
      const v4f h0 = hq[k4];
      const v4f h1 = hq[64 + k4];
      const v4f h2 = hq[128 + k4];
      const v4f h3 = hq[192 + k4];
      a0 += w0 * h0.x + w1 * h0.y + w2 * h0.z + w3 * h0.w;
      a1 += w0 * h1.x + w1 * h1.y + w2 * h1.z + w3 * h1.w;
      a2 += w0 * h2.x + w1 * h2.y + w2 * h2.z + w3 * h2.w;
      a3 += w0 * h3.x + w1 * h3.y + w2 * h3.z + w3 * h3.w;
    }
    red[(kq << 2) | 0][uP] = a0;
    red[(kq << 2) | 1][uP] = a1;
    red[(kq << 2) | 2][uP] = a2;
    red[(kq << 2) | 3][uP] = a3;
    __syncthreads();
    const v4f gv = red[bA][uA] + red[4 + bA][uA] + red[8 + bA][uA] + red[12 + bA][uA];
    const float iv = sigm(gv.x + dbi_), fv = sigm(gv.y + dbf_);
    const float gva = tanhf(gv.z + dbg_), ov = sigm(gv.w + dbo_);
    c = fv * c + iv * gva;
    hsF[p ^ 1][(bA << 8) | uA] = ov * tanhf(c);
    __syncthreads();
    p ^= 1;
  }

  // --- main loop: [attention_t || Wh·h_t] ; argmax ; Wi·din ; activation ---
  for (int t = 0; t < 256; ++t) {
    const int cnt = 256 - t;
    const bool act = (uA < cnt);
    const int sIdx = act ? (int)actS[bA][uA] : 0;

    // FUSED PHASE: attention row dot (L3 latency) hidden under Wh·h FMA (L2)
    const v4f* Arow = encS + ((((size_t)bG << 8) | (unsigned)sIdx) << 6);
    const v4f* hrow = ((const v4f*)&hsF[p][0]) + (bA << 6);
    const v4f* hq   = (const v4f*)&hsF[p][0];
    const v4f* Wh   = decWh4 + uP;
    {
      v4f a0 = (v4f)0.f, a1 = (v4f)0.f, a2 = (v4f)0.f, a3 = (v4f)0.f;
      float s0 = 0.f, s1 = 0.f, s2 = 0.f, s3 = 0.f;
#pragma unroll 4
      for (int kk = 0; kk < 16; ++kk) {
        const int k4 = k4b + kk;
        v4f e0 = (v4f)0.f, e1 = (v4f)0.f, e2 = (v4f)0.f, e3 = (v4f)0.f;
        if (act) {
          e0 = Arow[4 * kk + 0]; e1 = Arow[4 * kk + 1];
          e2 = Arow[4 * kk + 2]; e3 = Arow[4 * kk + 3];
        }
        const v4f w0 = Wh[(k4 * 4 + 0) << 8];
        const v4f w1 = Wh[(k4 * 4 + 1) << 8];
        const v4f w2 = Wh[(k4 * 4 + 2) << 8];
        const v4f w3 = Wh[(k4 * 4 + 3) << 8];
        const v4f h0 = hq[k4];
        const v4f h1 = hq[64 + k4];
        const v4f h2 = hq[128 + k4];
        const v4f h3 = hq[192 + k4];
        a0 += w0 * h0.x + w1 * h0.y + w2 * h0.z + w3 * h0.w;
        a1 += w0 * h1.x + w1 * h1.y + w2 * h1.z + w3 * h1.w;
        a2 += w0 * h2.x + w1 * h2.y + w2 * h2.z + w3 * h2.w;
        a3 += w0 * h3.x + w1 * h3.y + w2 * h3.z + w3 * h3.w;
        if (act) {
          const v4f f0 = hrow[4 * kk + 0], f1 = hrow[4 * kk + 1];
          const v4f f2 = hrow[4 * kk + 2], f3 = hrow[4 * kk + 3];
          s0 += e0.x * f0.x + e0.y * f0.y + e0.z * f0.z + e0.w * f0.w;
          s1 += e1.x * f1.x + e1.y * f1.y + e1.z * f1.z + e1.w * f1.w;
          s2 += e2.x * f2.x + e2.y * f2.y + e2.z * f2.z + e2.w * f2.w;
          s3 += e3.x * f3.x + e3.y * f3.y + e3.z * f3.z + e3.w * f3.w;
        }
      }
      // free the Wh accumulators NOW — nothing v4f stays live across argmax
      red[(kq << 2) | 0][uP] = a0;
      red[(kq << 2) | 1][uP] = a1;
      red[(kq << 2) | 2][uP] = a2;
      red[(kq << 2) | 3][uP] = a3;

      float bv = NEG_INF;
      int bi = 0x7fffffff;
      if (act) {
        const float sc = (s0 + s1) + (s2 + s3);
        unsigned kk0 = 0u, kk1 = (unsigned)t;     // threefry (exact, R1-R7)
        tf2(0u, 42u, kk0, kk1);
        unsigned y0 = 0u, y1 = (unsigned)((bG << 8) + sIdx);
        tf2(kk0, kk1, y0, y1);
        const unsigned bits = y0 ^ y1;
        const float fr = __uint_as_float((bits >> 9) | 0x3f800000u) - 1.0f;
        const float uu = (fr > 0.f) ? fr : 1.17549435e-38f;
        const float gum = -logf(-logf(uu));
        bv = sc + gum;
        bi = sIdx;
      }
#pragma unroll
      for (int off = 32; off; off >>= 1) {
        const float ov2 = __shfl_xor(bv, off, 64);
        const int oi2 = __shfl_xor(bi, off, 64);
        if (ov2 > bv || (ov2 == bv && oi2 < bi)) { bv = ov2; bi = oi2; }
      }
      if (l == 0) { partV[bA][uw] = bv; partI[bA][uw] = bi; }
    }
    __syncthreads();                              // S_D: argmax partials ready

    // all threads: combine argmax for ALL 4 batches (needed for Wi phase)
    int fiv[4];
#pragma unroll
    for (int bb = 0; bb < 4; ++bb) {
      float v = partV[bb][0]; int fi = partI[bb][0];
#pragma unroll
      for (int j = 1; j < 4; ++j) {
        const float vj = partV[bb][j];
        const int ij = partI[bb][j];
        if (vj > v || (vj == v && ij < fi)) { v = vj; fi = ij; }
      }
      fiv[bb] = fi;
    }
    if (uA == 0) {                                // one thread per batch
      const int fi = fiv[bA];
      out[(bG << 8) + t] = fi;
      const int pf = posS[bA][fi];                // swap-remove from active list
      const short ls = actS[bA][cnt - 1];
      actS[bA][pf] = ls;
      posS[bA][ls] = (short)pf;
    }

    // Wi·din partials; din rows are L2/L1-hot (attention just read them)
    {
      const v4f* Wi = decWi4 + uP;
      const v4f* r0 = encS + ((((size_t)(b0 + 0) << 8) | (unsigned)fiv[0]) << 6);
      const v4f* r1 = encS + ((((size_t)(b0 + 1) << 8) | (unsigned)fiv[1]) << 6);
      const v4f* r2 = encS + ((((size_t)(b0 + 2) << 8) | (unsigned)fiv[2]) << 6);
      const v4f* r3 = encS + ((((size_t)(b0 + 3) << 8) | (unsigned)fiv[3]) << 6);
      v4f a0 = (v4f)0.f, a1 = (v4f)0.f, a2 = (v4f)0.f, a3 = (v4f)0.f;
#pragma unroll 2
      for (int kk = 0; kk < 16; ++kk) {
        const int k4 = k4b + kk;
        const v4f w0 = Wi[(k4 * 4 + 0) << 8];
        const v4f w1 = Wi[(k4 * 4 + 1) << 8];
        const v4f w2 = Wi[(k4 * 4 + 2) << 8];
        const v4f w3 = Wi[(k4 * 4 + 3) << 8];
        const v4f d0 = r0[k4];
        const v4f d1 = r1[k4];
        const v4f d2 = r2[k4];
        const v4f d3 = r3[k4];
        a0 += w0 * d0.x + w1 * d0.y + w2 * d0.z + w3 * d0.w;
        a1 += w0 * d1.x + w1 * d1.y + w2 * d1.z + w3 * d1.w;
        a2 += w0 * d2.x + w1 * d2.y + w2 * d2.z + w3 * d2.w;
        a3 += w0 * d3.x + w1 * d3.y + w2 * d3.z + w3 * d3.w;
      }
      // accumulate onto the Wh partials stored pre-argmax (owner-only RMW)
      red[(kq << 2) | 0][uP] += a0;
      red[(kq << 2) | 1][uP] += a1;
      red[(kq << 2) | 2][uP] += a2;
      red[(kq << 2) | 3][uP] += a3;
    }
    __syncthreads();                              // S_B: partials ready

    // activation for (bA, uA) -> h_{t+1}
    const v4f gv = red[bA][uA] + red[4 + bA][uA] + red[8 + bA][uA] + red[12 + bA][uA];
    const float iv = sigm(gv.x + dbi_), fv = sigm(gv.y + dbf_);
    const float gva = tanhf(gv.z + dbg_), ov = sigm(gv.w + dbo_);
    c = fv * c + iv * gva;
    hsF[p ^ 1][(bA << 8) | uA] = ov * tanhf(c);
    __syncthreads();                              // S_C: new h ready
    p ^= 1;
  }
}

extern "C" void kernel_launch(void* const* d_in, const int* in_sizes, int n_in,
                              void* d_out, int out_size, void* d_ws, size_t ws_size,
                              hipStream_t stream) {
  (void)in_sizes; (void)n_in; (void)out_size;
  if (ws_size < WS_NEEDED) return;   // need ~139 MB scratch

  const float* inp = (const float*)d_in[0];
  const float* eWi = (const float*)d_in[1];
  const float* eWh = (const float*)d_in[2];
  const float* eBi = (const float*)d_in[3];
  const float* eBh = (const float*)d_in[4];
  const float* dWi = (const float*)d_in[5];
  const float* dWh = (const float*)d_in[6];
  const float* dBi = (const float*)d_in[7];
  const float* dBh = (const float*)d_in[8];
  int* out = (int*)d_out;
  float* wsf = (float*)d_ws;

  hipLaunchKernelGGL(repack_k, dim3(256), dim3(256), 0, stream, eWh, dWi, dWh, wsf);
  hipLaunchKernelGGL(ptrnet_kernel, dim3(128), dim3(1024), 0, stream,
                     inp, eWi, eBi, eBh, dBi, dBh, out, wsf);
}

// Round 9
// 30524.902 us; speedup vs baseline: 1.5538x; 1.0014x over previous
//
#include <hip/hip_runtime.h>
#include <cstdint>
#include <cstddef>

// ============================================================================
// PointerNet: encoder LSTM (B=512,S=256,D=2,H=256) + autoregressive pointer
// decode with jax.random.categorical (threefry2x32 partitionable, key 42).
// Output: int32 indices [512][256], trajectory-exact vs JAX reference.
//
// R9 = R8 structure (fused attention_t + Wh·h_t; argmax; Wi·din from L2-hot
// encS row; activation; 3 barriers/step) with the register allocator PINNED:
//  - R8 evidence: __launch_bounds__(1024,4) gives the backend range [4,8]
//    waves/EU; LDS 78336 (2 blocks/CU possible) made it target 8 -> 64-VGPR
//    cap -> ~40 regs/thread spilled (33 GB WRITE + 27 GB FETCH of scratch).
//  - Fix 1: __attribute__((amdgpu_waves_per_eu(4,4))) pins [4,4] -> 128 VGPR.
//  - Fix 2: red[] padded to 17 rows -> LDS 82432 > 80 KB -> occupancy calc
//    itself says 1 block/CU. (R6 ran fine at this LDS size.)
// Everything else byte-identical to R8; this cleanly tests the R7 fusion
// theory (L3 attention latency hidden under Wh FMA window) without spills.
// ============================================================================

typedef float v4f __attribute__((ext_vector_type(4)));

#define WS_ENCW4_OFF  (2u << 20)                    // [256 k][256 u][4 g] f32
#define WS_DECWI4_OFF (3u << 20)
#define WS_DECWH4_OFF (4u << 20)
#define WS_ENCS_OFF   (5u << 20)                    // [512 b][256 s][256 k] f32
#define WS_NEEDED     ((size_t)(5u << 20) + (size_t)512 * 256 * 256 * 4)

__device__ __forceinline__ unsigned rotl32(unsigned x, int r) {
  return (x << r) | (x >> (32 - r));
}
__device__ __forceinline__ float sigm(float x) { return 1.f / (1.f + expf(-x)); }

// Threefry-2x32, 20 rounds (jax._src.prng schedule) — verified exact R1-R8.
__device__ __forceinline__ void tf2(unsigned k0, unsigned k1,
                                    unsigned& x0, unsigned& x1) {
  const unsigned k2 = k0 ^ k1 ^ 0x1BD11BDAu;
  x0 += k0; x1 += k1;
  x0 += x1; x1 = rotl32(x1, 13); x1 ^= x0;
  x0 += x1; x1 = rotl32(x1, 15); x1 ^= x0;
  x0 += x1; x1 = rotl32(x1, 26); x1 ^= x0;
  x0 += x1; x1 = rotl32(x1,  6); x1 ^= x0;
  x0 += k1; x1 += k2 + 1u;
  x0 += x1; x1 = rotl32(x1, 17); x1 ^= x0;
  x0 += x1; x1 = rotl32(x1, 29); x1 ^= x0;
  x0 += x1; x1 = rotl32(x1, 16); x1 ^= x0;
  x0 += x1; x1 = rotl32(x1, 24); x1 ^= x0;
  x0 += k2; x1 += k0 + 2u;
  x0 += x1; x1 = rotl32(x1, 13); x1 ^= x0;
  x0 += x1; x1 = rotl32(x1, 15); x1 ^= x0;
  x0 += x1; x1 = rotl32(x1, 26); x1 ^= x0;
  x0 += x1; x1 = rotl32(x1,  6); x1 ^= x0;
  x0 += k0; x1 += k1 + 3u;
  x0 += x1; x1 = rotl32(x1, 17); x1 ^= x0;
  x0 += x1; x1 = rotl32(x1, 29); x1 ^= x0;
  x0 += x1; x1 = rotl32(x1, 16); x1 ^= x0;
  x0 += x1; x1 = rotl32(x1, 24); x1 ^= x0;
  x0 += k1; x1 += k2 + 4u;
  x0 += x1; x1 = rotl32(x1, 13); x1 ^= x0;
  x0 += x1; x1 = rotl32(x1, 15); x1 ^= x0;
  x0 += x1; x1 = rotl32(x1, 26); x1 ^= x0;
  x0 += x1; x1 = rotl32(x1,  6); x1 ^= x0;
  x0 += k2; x1 += k0 + 5u;
}

// Repack W [1024 rows][256 k] row-major -> [k][u][gate] (float4 per (k,u)).
__global__ void repack_k(const float* __restrict__ eWh,
                         const float* __restrict__ dWi,
                         const float* __restrict__ dWh,
                         float* __restrict__ ws) {
  float* encW4 = (float*)((char*)ws + WS_ENCW4_OFF);
  float* decWi4 = (float*)((char*)ws + WS_DECWI4_OFF);
  float* decWh4 = (float*)((char*)ws + WS_DECWH4_OFF);
  const int n = blockIdx.x * blockDim.x + threadIdx.x;   // 65536 = 256k x 256u
  if (n >= 65536) return;
  const int k = n >> 8, u = n & 255;
#pragma unroll
  for (int g = 0; g < 4; ++g) {
    const int src = ((g << 8) + u) * 256 + k;
    const int dst = (n << 2) + g;
    encW4[dst] = eWh[src];
    decWi4[dst] = dWi[src];
    decWh4[dst] = dWh[src];
  }
}

__global__ void __launch_bounds__(1024)
__attribute__((amdgpu_waves_per_eu(4, 4)))
ptrnet_kernel(const float* __restrict__ inp,    // [512][256][2]
              const float* __restrict__ eWi,    // [1024][2]
              const float* __restrict__ eBi, const float* __restrict__ eBh,
              const float* __restrict__ dBi, const float* __restrict__ dBh,
              int* __restrict__ out,            // [512][256]
              float* __restrict__ ws) {
  const int tid  = threadIdx.x;
  const int wave = tid >> 6, l = tid & 63;
  const int kq   = wave >> 2;               // K-quarter 0..3 (16 k4 each)
  const int uw   = wave & 3;                // u-slice 0..3
  const int uP   = (uw << 6) | l;           // this lane's unit in P1 (matmul)
  const int k4b  = kq << 4;
  const int bA   = tid >> 8;                // this thread's batch in P2/attn
  const int uA   = tid & 255;               // this thread's unit/slot in P2/attn
  const int b0   = blockIdx.x << 2;
  const int bG   = b0 + bA;

  const v4f* encW4  = (const v4f*)((char*)ws + WS_ENCW4_OFF);
  const v4f* decWi4 = (const v4f*)((char*)ws + WS_DECWI4_OFF);
  const v4f* decWh4 = (const v4f*)((char*)ws + WS_DECWH4_OFF);
  v4f* encS = (v4f*)((char*)ws + WS_ENCS_OFF);   // [b][s][64 k4] v4f

  __shared__ __align__(16) float hsF[2][1024];   // h dbuf: [buf][b*256+u]
  __shared__ __align__(16) v4f red[17][256];     // partials [kq*4+b][u]; row 16
                                                 // = pad -> LDS>80KB -> 1 blk/CU
  __shared__ short actS[4][256];                 // compacted active s list
  __shared__ short posS[4][256];                 // position of s in actS
  __shared__ float partV[4][4];
  __shared__ int   partI[4][4];

  // ---- activation-thread constants (keyed by uA) ----
  const float ebi_ = eBi[uA] + eBh[uA];
  const float ebf_ = eBi[256 + uA] + eBh[256 + uA];
  const float ebg_ = eBi[512 + uA] + eBh[512 + uA];
  const float ebo_ = eBi[768 + uA] + eBh[768 + uA];
  const float wxi0 = eWi[2 * uA], wxi1 = eWi[2 * uA + 1];
  const float wxf0 = eWi[2 * (256 + uA)], wxf1 = eWi[2 * (256 + uA) + 1];
  const float wxg0 = eWi[2 * (512 + uA)], wxg1 = eWi[2 * (512 + uA) + 1];
  const float wxo0 = eWi[2 * (768 + uA)], wxo1 = eWi[2 * (768 + uA) + 1];

  hsF[0][tid] = 0.f;
  __syncthreads();

  float c = 0.f;        // cell state for (bG, uA) — register-resident throughout
  int p = 0;

  // ---------------- encoder: 256 steps ----------------
  for (int t = 0; t < 256; ++t) {
    v4f a0 = (v4f)0.f, a1 = (v4f)0.f, a2 = (v4f)0.f, a3 = (v4f)0.f;
    const v4f* Wp = encW4 + uP;
    const v4f* hq = (const v4f*)&hsF[p][0];       // [4 b][64 k4]
#pragma unroll 2
    for (int kk = 0; kk < 16; ++kk) {
      const int k4 = k4b + kk;
      const v4f w0 = Wp[(k4 * 4 + 0) << 8];
      const v4f w1 = Wp[(k4 * 4 + 1) << 8];
      const v4f w2 = Wp[(k4 * 4 + 2) << 8];
      const v4f w3 = Wp[(k4 * 4 + 3) << 8];
      const v4f h0 = hq[k4];
      const v4f h1 = hq[64 + k4];
      const v4f h2 = hq[128 + k4];
      const v4f h3 = hq[192 + k4];
      a0 += w0 * h0.x + w1 * h0.y + w2 * h0.z + w3 * h0.w;
      a1 += w0 * h1.x + w1 * h1.y + w2 * h1.z + w3 * h1.w;
      a2 += w0 * h2.x + w1 * h2.y + w2 * h2.z + w3 * h2.w;
      a3 += w0 * h3.x + w1 * h3.y + w2 * h3.z + w3 * h3.w;
    }
    red[(kq << 2) | 0][uP] = a0;
    red[(kq << 2) | 1][uP] = a1;
    red[(kq << 2) | 2][uP] = a2;
    red[(kq << 2) | 3][uP] = a3;
    __syncthreads();                              // S_B: partials ready
    const v4f gv = red[bA][uA] + red[4 + bA][uA] + red[8 + bA][uA] + red[12 + bA][uA];
    const float2 xv = *(const float2*)(inp + (((bG) << 8) + t) * 2);
    const float ai = gv.x + ebi_ + wxi0 * xv.x + wxi1 * xv.y;
    const float af = gv.y + ebf_ + wxf0 * xv.x + wxf1 * xv.y;
    const float ag = gv.z + ebg_ + wxg0 * xv.x + wxg1 * xv.y;
    const float ao = gv.w + ebo_ + wxo0 * xv.x + wxo1 * xv.y;
    const float iv = sigm(ai), fv = sigm(af), gva = tanhf(ag), ov = sigm(ao);
    c = fv * c + iv * gva;
    const float hn = ov * tanhf(c);
    hsF[p ^ 1][(bA << 8) | uA] = hn;
    ((float*)encS)[(((bG << 8) | t) << 8) | uA] = hn;   // s-major row store
    __syncthreads();                              // S_C: new h ready
    p ^= 1;
  }

  // ---------------- decoder ----------------
  const float dbi_ = dBi[uA] + dBh[uA];
  const float dbf_ = dBi[256 + uA] + dBh[256 + uA];
  const float dbg_ = dBi[512 + uA] + dBh[512 + uA];
  const float dbo_ = dBi[768 + uA] + dBh[768 + uA];
  const float NEG_INF = __int_as_float((int)0xff800000);

  actS[bA][uA] = (short)uA;
  posS[bA][uA] = (short)uA;

  // --- prologue: decoder LSTM step 0 (din = 0) ---
  {
    v4f a0 = (v4f)0.f, a1 = (v4f)0.f, a2 = (v4f)0.f, a3 = (v4f)0.f;
    const v4f* Wh = decWh4 + uP;
    const v4f* hq = (const v4f*)&hsF[p][0];
#pragma unroll 2
    for (int kk = 0; kk < 16; ++kk) {
      const int k4 = k4b + kk;
      const v4f w0 = Wh[(k4 * 4 + 0) << 8];
      const v4f w1 = Wh[(k4 * 4 + 1) << 8];
      const v4f w2 = Wh[(k4 * 4 + 2) << 8];
      const v4f w3 = Wh[(k4 * 4 + 3) << 8];
      const v4f h0 = hq[k4];
      const v4f h1 = hq[64 + k4];
      const v4f h2 = hq[128 + k4];
      const v4f h3 = hq[192 + k4];
      a0 += w0 * h0.x + w1 * h0.y + w2 * h0.z + w3 * h0.w;
      a1 += w0 * h1.x + w1 * h1.y + w2 * h1.z + w3 * h1.w;
      a2 += w0 * h2.x + w1 * h2.y + w2 * h2.z + w3 * h2.w;
      a3 += w0 * h3.x + w1 * h3.y + w2 * h3.z + w3 * h3.w;
    }
    red[(kq << 2) | 0][uP] = a0;
    red[(kq << 2) | 1][uP] = a1;
    red[(kq << 2) | 2][uP] = a2;
    red[(kq << 2) | 3][uP] = a3;
    __syncthreads();
    const v4f gv = red[bA][uA] + red[4 + bA][uA] + red[8 + bA][uA] + red[12 + bA][uA];
    const float iv = sigm(gv.x + dbi_), fv = sigm(gv.y + dbf_);
    const float gva = tanhf(gv.z + dbg_), ov = sigm(gv.w + dbo_);
    c = fv * c + iv * gva;
    hsF[p ^ 1][(bA << 8) | uA] = ov * tanhf(c);
    __syncthreads();
    p ^= 1;
  }

  // --- main loop: [attention_t || Wh·h_t] ; argmax ; Wi·din ; activation ---
  for (int t = 0; t < 256; ++t) {
    const int cnt = 256 - t;
    const bool act = (uA < cnt);
    const int sIdx = act ? (int)actS[bA][uA] : 0;

    // FUSED PHASE: attention row dot (L3 latency) hidden under Wh·h FMA (L2)
    const v4f* Arow = encS + ((((size_t)bG << 8) | (unsigned)sIdx) << 6);
    const v4f* hrow = ((const v4f*)&hsF[p][0]) + (bA << 6);
    const v4f* hq   = (const v4f*)&hsF[p][0];
    const v4f* Wh   = decWh4 + uP;
    {
      v4f a0 = (v4f)0.f, a1 = (v4f)0.f, a2 = (v4f)0.f, a3 = (v4f)0.f;
      float s0 = 0.f, s1 = 0.f, s2 = 0.f, s3 = 0.f;
#pragma unroll 4
      for (int kk = 0; kk < 16; ++kk) {
        const int k4 = k4b + kk;
        v4f e0 = (v4f)0.f, e1 = (v4f)0.f, e2 = (v4f)0.f, e3 = (v4f)0.f;
        if (act) {
          e0 = Arow[4 * kk + 0]; e1 = Arow[4 * kk + 1];
          e2 = Arow[4 * kk + 2]; e3 = Arow[4 * kk + 3];
        }
        const v4f w0 = Wh[(k4 * 4 + 0) << 8];
        const v4f w1 = Wh[(k4 * 4 + 1) << 8];
        const v4f w2 = Wh[(k4 * 4 + 2) << 8];
        const v4f w3 = Wh[(k4 * 4 + 3) << 8];
        const v4f h0 = hq[k4];
        const v4f h1 = hq[64 + k4];
        const v4f h2 = hq[128 + k4];
        const v4f h3 = hq[192 + k4];
        a0 += w0 * h0.x + w1 * h0.y + w2 * h0.z + w3 * h0.w;
        a1 += w0 * h1.x + w1 * h1.y + w2 * h1.z + w3 * h1.w;
        a2 += w0 * h2.x + w1 * h2.y + w2 * h2.z + w3 * h2.w;
        a3 += w0 * h3.x + w1 * h3.y + w2 * h3.z + w3 * h3.w;
        if (act) {
          const v4f f0 = hrow[4 * kk + 0], f1 = hrow[4 * kk + 1];
          const v4f f2 = hrow[4 * kk + 2], f3 = hrow[4 * kk + 3];
          s0 += e0.x * f0.x + e0.y * f0.y + e0.z * f0.z + e0.w * f0.w;
          s1 += e1.x * f1.x + e1.y * f1.y + e1.z * f1.z + e1.w * f1.w;
          s2 += e2.x * f2.x + e2.y * f2.y + e2.z * f2.z + e2.w * f2.w;
          s3 += e3.x * f3.x + e3.y * f3.y + e3.z * f3.z + e3.w * f3.w;
        }
      }
      // free the Wh accumulators NOW — nothing v4f stays live across argmax
      red[(kq << 2) | 0][uP] = a0;
      red[(kq << 2) | 1][uP] = a1;
      red[(kq << 2) | 2][uP] = a2;
      red[(kq << 2) | 3][uP] = a3;

      float bv = NEG_INF;
      int bi = 0x7fffffff;
      if (act) {
        const float sc = (s0 + s1) + (s2 + s3);
        unsigned kk0 = 0u, kk1 = (unsigned)t;     // threefry (exact, R1-R8)
        tf2(0u, 42u, kk0, kk1);
        unsigned y0 = 0u, y1 = (unsigned)((bG << 8) + sIdx);
        tf2(kk0, kk1, y0, y1);
        const unsigned bits = y0 ^ y1;
        const float fr = __uint_as_float((bits >> 9) | 0x3f800000u) - 1.0f;
        const float uu = (fr > 0.f) ? fr : 1.17549435e-38f;
        const float gum = -logf(-logf(uu));
        bv = sc + gum;
        bi = sIdx;
      }
#pragma unroll
      for (int off = 32; off; off >>= 1) {
        const float ov2 = __shfl_xor(bv, off, 64);
        const int oi2 = __shfl_xor(bi, off, 64);
        if (ov2 > bv || (ov2 == bv && oi2 < bi)) { bv = ov2; bi = oi2; }
      }
      if (l == 0) { partV[bA][uw] = bv; partI[bA][uw] = bi; }
    }
    __syncthreads();                              // S_D: argmax partials ready

    // all threads: combine argmax for ALL 4 batches (needed for Wi phase)
    int fiv[4];
#pragma unroll
    for (int bb = 0; bb < 4; ++bb) {
      float v = partV[bb][0]; int fi = partI[bb][0];
#pragma unroll
      for (int j = 1; j < 4; ++j) {
        const float vj = partV[bb][j];
        const int ij = partI[bb][j];
        if (vj > v || (vj == v && ij < fi)) { v = vj; fi = ij; }
      }
      fiv[bb] = fi;
    }
    if (uA == 0) {                                // one thread per batch
      const int fi = fiv[bA];
      out[(bG << 8) + t] = fi;
      const int pf = posS[bA][fi];                // swap-remove from active list
      const short ls = actS[bA][cnt - 1];
      actS[bA][pf] = ls;
      posS[bA][ls] = (short)pf;
    }

    // Wi·din partials; din rows are L2/L1-hot (attention just read them)
    {
      const v4f* Wi = decWi4 + uP;
      const v4f* r0 = encS + ((((size_t)(b0 + 0) << 8) | (unsigned)fiv[0]) << 6);
      const v4f* r1 = encS + ((((size_t)(b0 + 1) << 8) | (unsigned)fiv[1]) << 6);
      const v4f* r2 = encS + ((((size_t)(b0 + 2) << 8) | (unsigned)fiv[2]) << 6);
      const v4f* r3 = encS + ((((size_t)(b0 + 3) << 8) | (unsigned)fiv[3]) << 6);
      v4f a0 = (v4f)0.f, a1 = (v4f)0.f, a2 = (v4f)0.f, a3 = (v4f)0.f;
#pragma unroll 2
      for (int kk = 0; kk < 16; ++kk) {
        const int k4 = k4b + kk;
        const v4f w0 = Wi[(k4 * 4 + 0) << 8];
        const v4f w1 = Wi[(k4 * 4 + 1) << 8];
        const v4f w2 = Wi[(k4 * 4 + 2) << 8];
        const v4f w3 = Wi[(k4 * 4 + 3) << 8];
        const v4f d0 = r0[k4];
        const v4f d1 = r1[k4];
        const v4f d2 = r2[k4];
        const v4f d3 = r3[k4];
        a0 += w0 * d0.x + w1 * d0.y + w2 * d0.z + w3 * d0.w;
        a1 += w0 * d1.x + w1 * d1.y + w2 * d1.z + w3 * d1.w;
        a2 += w0 * d2.x + w1 * d2.y + w2 * d2.z + w3 * d2.w;
        a3 += w0 * d3.x + w1 * d3.y + w2 * d3.z + w3 * d3.w;
      }
      // accumulate onto the Wh partials stored pre-argmax (owner-only RMW)
      red[(kq << 2) | 0][uP] += a0;
      red[(kq << 2) | 1][uP] += a1;
      red[(kq << 2) | 2][uP] += a2;
      red[(kq << 2) | 3][uP] += a3;
    }
    __syncthreads();                              // S_B: partials ready

    // activation for (bA, uA) -> h_{t+1}
    const v4f gv = red[bA][uA] + red[4 + bA][uA] + red[8 + bA][uA] + red[12 + bA][uA];
    const float iv = sigm(gv.x + dbi_), fv = sigm(gv.y + dbf_);
    const float gva = tanhf(gv.z + dbg_), ov = sigm(gv.w + dbo_);
    c = fv * c + iv * gva;
    hsF[p ^ 1][(bA << 8) | uA] = ov * tanhf(c);
    __syncthreads();                              // S_C: new h ready
    p ^= 1;
  }
}

extern "C" void kernel_launch(void* const* d_in, const int* in_sizes, int n_in,
                              void* d_out, int out_size, void* d_ws, size_t ws_size,
                              hipStream_t stream) {
  (void)in_sizes; (void)n_in; (void)out_size;
  if (ws_size < WS_NEEDED) return;   // need ~139 MB scratch

  const float* inp = (const float*)d_in[0];
  const float* eWi = (const float*)d_in[1];
  const float* eWh = (const float*)d_in[2];
  const float* eBi = (const float*)d_in[3];
  const float* eBh = (const float*)d_in[4];
  const float* dWi = (const float*)d_in[5];
  const float* dWh = (const float*)d_in[6];
  const float* dBi = (const float*)d_in[7];
  const float* dBh = (const float*)d_in[8];
  int* out = (int*)d_out;
  float* wsf = (float*)d_ws;

  hipLaunchKernelGGL(repack_k, dim3(256), dim3(256), 0, stream, eWh, dWi, dWh, wsf);
  hipLaunchKernelGGL(ptrnet_kernel, dim3(128), dim3(1024), 0, stream,
                     inp, eWi, eBi, eBh, dBi, dBh, out, wsf);
}